// Round 1
// baseline (183159.436 us; speedup 1.0000x reference)
//
#include <hip/hip_runtime.h>
#include <cstdint>

// XLA CPU emits unfused mul/add (no fast-math, no contraction). hipcc defaults
// to -ffp-contract=fast -> must disable to mirror rounding exactly.
#pragma clang fp contract(off)

// ---- numerics-variant knobs (iterate in later rounds if absmax != 0) ----
#define RNG_VARIANT 0    // 0: threefry partitionable, counter=(0,j), bits=o0^o1
                         // 1: partitionable, bits=o0
                         // 2: legacy split-halves counter scheme
#define GEMV_VARIANT 0   // 0: XLA tiled gemv: 8-wide chunks + pairwise hsum + scalar k=48,49 (no FMA)
                         // 1: plain sequential k=0..49 mul+add
#define LOGIT_VARIANT 0  // 0: Eigen-style sequential FMA;  1: sequential mul+add

#define HH 50
#define H3 150
#define SORB 64
#define NSAMP 4096
#define TOT (SORB * NSAMP)

// ---- XLA CPU EmitFastTanh (llvm_ir/math_ops.cc), with_fma = false ----
__device__ __forceinline__ float xla_tanh(float x) {
  const float kClamp = 7.90531110763549805f;
  float ax = fabsf(x);
  float xc = fminf(fmaxf(x, -kClamp), kClamp);
  float x2 = xc * xc;
  float p = -2.76076847742355e-16f;
  p = x2 * p + 2.00018790482477e-13f;
  p = x2 * p + -8.60467152213735e-11f;
  p = x2 * p + 5.12229709037114e-08f;
  p = x2 * p + 1.48572235717979e-05f;
  p = x2 * p + 6.37261928875436e-04f;
  p = x2 * p + 4.89352455891786e-03f;
  p = xc * p;
  float q = 1.19825839466702e-06f;
  q = x2 * q + 1.18534705686654e-04f;
  q = x2 * q + 2.26843463243900e-03f;
  q = x2 * q + 4.89352518554385e-03f;
  float r = p / q;
  return (ax < 0.0004f) ? x : r;
}

// XLA HLO kLogistic: 0.5 + 0.5 * tanh(0.5 * x)
__device__ __forceinline__ float xla_logistic(float x) {
  return 0.5f + 0.5f * xla_tanh(x * 0.5f);
}

// correctly-rounded f32 exp (matches glibc expf essentially always)
__device__ __forceinline__ float exp_cr(float x) {
  return (float)exp((double)x);
}

// ---- bit-exact Threefry-2x32 (20 rounds), as in jax/_src/prng.py ----
__device__ __forceinline__ void tf2x32(uint32_t k0, uint32_t k1,
                                       uint32_t c0, uint32_t c1,
                                       uint32_t& o0, uint32_t& o1) {
  uint32_t k2 = k0 ^ k1 ^ 0x1BD11BDAu;
  uint32_t x0 = c0 + k0, x1 = c1 + k1;
#define TF_R(d) { x0 += x1; x1 = (x1 << (d)) | (x1 >> (32 - (d))); x1 ^= x0; }
#define TF_GA TF_R(13) TF_R(15) TF_R(26) TF_R(6)
#define TF_GB TF_R(17) TF_R(29) TF_R(16) TF_R(24)
  TF_GA; x0 += k1; x1 += k2 + 1u;
  TF_GB; x0 += k2; x1 += k0 + 2u;
  TF_GA; x0 += k0; x1 += k1 + 3u;
  TF_GB; x0 += k1; x1 += k2 + 4u;
  TF_GA; x0 += k2; x1 += k0 + 5u;
#undef TF_GB
#undef TF_GA
#undef TF_R
  o0 = x0; o1 = x1;
}

// u_{i,j} = jax.random.uniform(fold_in(key(42), i), (4096,))[j]
__device__ __forceinline__ float u_for_cell(int cc) {
  int ii = cc >> 12;
  int jj = cc & (NSAMP - 1);
  uint32_t k0, k1;
  tf2x32(0u, 42u, 0u, (uint32_t)ii, k0, k1);   // fold_in: threefry(key, seed(i)=[0,i])
  uint32_t b0, b1, bits;
#if RNG_VARIANT == 0
  tf2x32(k0, k1, 0u, (uint32_t)jj, b0, b1);
  bits = b0 ^ b1;
#elif RNG_VARIANT == 1
  tf2x32(k0, k1, 0u, (uint32_t)jj, b0, b1);
  bits = b0;
#else
  if (jj < NSAMP / 2) { tf2x32(k0, k1, (uint32_t)jj, (uint32_t)(jj + NSAMP / 2), b0, b1); bits = b0; }
  else                { tf2x32(k0, k1, (uint32_t)(jj - NSAMP / 2), (uint32_t)jj, b0, b1); bits = b1; }
#endif
  return __uint_as_float((bits >> 9) | 0x3f800000u) - 1.0f;
}

// Single workgroup runs the entire 262144-cell sequential chain.
// Threads 0..149: gemv rows (w_hh row in VGPRs). Threads 0..49: gates.
// Threads 192..207: lagged sampling (batches of 16 cells, 1 batch behind).
// Threads 208..223: threefry uniform pre-generation (1 batch ahead).
extern "C" __global__ void __launch_bounds__(256, 1)
ARSampler_59244778881183_kernel(const float* __restrict__ w_ih,
                                const float* __restrict__ w_hh,
                                const float* __restrict__ b_ih,
                                const float* __restrict__ b_hh,
                                const float* __restrict__ fc_w,
                                const float* __restrict__ fc_b,
                                int* __restrict__ out) {
  __shared__ float sh_h[64];               // current hidden state (50 used)
  __shared__ float sh_gh[160];             // W_hh @ h + b_hh (150 used)
  __shared__ float sh_xp[3][160];          // xp for bit=0 / bit=1 / x=0 (step 0)
  __shared__ float sh_fcw[2][56];
  __shared__ float sh_fcb[2];
  __shared__ float sh_outs[32][56];        // ring of h_new (sampling lags chain)
  __shared__ float sh_u[2][16];            // pre-generated uniforms, ping-pong
  __shared__ float sh_nu[NSAMP];           // running num_up per sample
  __shared__ unsigned char sh_bits[2][NSAMP]; // sampled bit per (row parity, j)

  const int t = threadIdx.x;

  // ---- init (all state re-derived every launch: deterministic replay) ----
  for (int idx = t; idx < H3; idx += 256) {
    float b = b_ih[idx];
    sh_xp[0][idx] = w_ih[idx * 2 + 0] + b;   // exact: (1*w + 0*w') + b == w + b
    sh_xp[1][idx] = w_ih[idx * 2 + 1] + b;
    sh_xp[2][idx] = b;                        // step 0: x = 0
  }
  for (int idx = t; idx < 2 * HH; idx += 256) sh_fcw[idx / HH][idx % HH] = fc_w[idx];
  if (t < 2) sh_fcb[t] = fc_b[t];
  if (t < HH) sh_h[t] = 0.0f;
  for (int idx = t; idx < NSAMP; idx += 256) sh_nu[idx] = 0.0f;

  float wreg[HH];
  float bhh = 0.0f;
  if (t < H3) {
#pragma unroll
    for (int k = 0; k < HH; ++k) wreg[k] = w_hh[t * HH + k];
    bhh = b_hh[t];
  }
  __syncthreads();

  // ---- lagged sampler: head + mask + multinomial for one cell ----
  auto do_sample = [&](int cbase, int ts) {
    int cc = cbase + ts;
    int ii = cc >> 12;
    int jj = cc & (NSAMP - 1);
    const float* o = sh_outs[cc & 31];
    float l0, l1;
#if LOGIT_VARIANT == 0
    l0 = 0.0f; l1 = 0.0f;
#pragma unroll
    for (int k = 0; k < HH; ++k) {
      l0 = fmaf(o[k], sh_fcw[0][k], l0);    // Eigen gebp: sequential-k FMA
      l1 = fmaf(o[k], sh_fcw[1][k], l1);
    }
#else
    l0 = o[0] * sh_fcw[0][0]; l1 = o[0] * sh_fcw[1][0];
#pragma unroll
    for (int k = 1; k < HH; ++k) {
      l0 = l0 + o[k] * sh_fcw[0][k];
      l1 = l1 + o[k] * sh_fcw[1][k];
    }
#endif
    l0 = l0 + sh_fcb[0];
    l1 = l1 + sh_fcb[1];
    // sqrt(softmax(logits))
    float mx = fmaxf(l0, l1);
    float e0 = exp_cr(l0 - mx);
    float e1 = exp_cr(l1 - mx);
    float se = e0 + e1;
    float o0 = sqrtf(e0 / se);
    float o1 = sqrtf(e1 / se);
    float nuo = sh_nu[jj];
    if (ii >= SORB / 2) {
      float fi = (float)ii;
      float ndown = fi - nuo;
      float ad = ((31.0f - ndown) >= 0.0f) ? 1.0f : 0.0f;  // heaviside(baseline - num_down)
      float au = ((31.0f - nuo) >= 0.0f) ? 1.0f : 0.0f;    // heaviside(baseline - num_up)
      float m0 = o0 * ad;
      float m1 = o1 * au;
      float nr = sqrtf(m0 * m0 + m1 * m1);
      nr = fmaxf(nr, 1e-30f);
      o0 = m0 / nr;
      o1 = m1 / nr;
    }
    float den = fmaxf(o0 + o1, 1e-30f);
    float p0 = o0 / den;
    float u = sh_u[(cbase >> 4) & 1][ts];
    int s = (u >= p0) ? 1 : 0;
    sh_nu[jj] = nuo + (float)s;
    sh_bits[ii & 1][jj] = (unsigned char)s;
    out[jj * SORB + ii] = s;   // samples.T -> out[j][i]
  };

  // ---- the 262144-cell sequential chain ----
  for (int c = 0; c < TOT; ++c) {
    const int i = c >> 12;
    const int j = c & (NSAMP - 1);

    // phase 1: gh = W_hh @ h + b_hh   (samplers / u-prep piggyback on idle waves)
    if (t < H3) {
      float hv[HH];
#pragma unroll
      for (int k = 0; k < HH; ++k) hv[k] = sh_h[k];
#if GEMV_VARIANT == 0
      // XLA RowMajorMatrixVectorProduct, vector width 8, no FMA:
      float acc[8];
#pragma unroll
      for (int l = 0; l < 8; ++l) acc[l] = wreg[l] * hv[l];
#pragma unroll
      for (int ch = 1; ch < 6; ++ch) {
#pragma unroll
        for (int l = 0; l < 8; ++l) acc[l] = acc[l] + wreg[8 * ch + l] * hv[8 * ch + l];
      }
      float s04 = acc[0] + acc[4];
      float s15 = acc[1] + acc[5];
      float s26 = acc[2] + acc[6];
      float s37 = acc[3] + acc[7];
      float t0 = s04 + s26;
      float t1 = s15 + s37;
      float dot = t0 + t1;
      dot = dot + wreg[48] * hv[48];   // scalar k-epilogue
      dot = dot + wreg[49] * hv[49];
#else
      float dot = wreg[0] * hv[0];
#pragma unroll
      for (int k = 1; k < HH; ++k) dot = dot + wreg[k] * hv[k];
#endif
      sh_gh[t] = dot + bhh;
    } else if ((c & 15) == 0) {
      if (t >= 192 && t < 208) {
        if (c > 0) do_sample(c - 16, t - 192);          // sample previous batch
      } else if (t >= 208 && t < 224) {
        sh_u[(c >> 4) & 1][t - 208] = u_for_cell(c + (t - 208));  // prep current batch
      }
    }
    __syncthreads();

    // phase 2: GRU gates -> h_new
    if (t < HH) {
      int sel = (i == 0) ? 2 : (int)sh_bits[(i - 1) & 1][j];
      float xr = sh_xp[sel][t];
      float xz = sh_xp[sel][t + 50];
      float xn = sh_xp[sel][t + 100];
      float hr = sh_gh[t];
      float hz = sh_gh[t + 50];
      float hn = sh_gh[t + 100];
      float r = xla_logistic(xr + hr);
      float z = xla_logistic(xz + hz);
      float rhn = r * hn;
      float n = xla_tanh(xn + rhn);
      float hold = sh_h[t];
      float omz = 1.0f - z;
      float hnew = omz * n + z * hold;   // (1-z)*n + z*h, unfused
      sh_h[t] = hnew;
      sh_outs[j & 31][t] = hnew;
    }
    __syncthreads();
  }

  // flush: sample the final 16 cells
  if (t >= 192 && t < 208) do_sample(TOT - 16, t - 192);
}

extern "C" void kernel_launch(void* const* d_in, const int* in_sizes, int n_in,
                              void* d_out, int out_size, void* d_ws, size_t ws_size,
                              hipStream_t stream) {
  (void)in_sizes; (void)n_in; (void)out_size; (void)d_ws; (void)ws_size;
  const float* w_ih = (const float*)d_in[0];
  const float* w_hh = (const float*)d_in[1];
  const float* b_ih = (const float*)d_in[2];
  const float* b_hh = (const float*)d_in[3];
  const float* fc_w = (const float*)d_in[4];
  const float* fc_b = (const float*)d_in[5];
  hipLaunchKernelGGL(ARSampler_59244778881183_kernel, dim3(1), dim3(256), 0, stream,
                     w_ih, w_hh, b_ih, b_hh, fc_w, fc_b, (int*)d_out);
}

// Round 3
// 169621.155 us; speedup vs baseline: 1.0798x; 1.0798x over previous
//
#include <hip/hip_runtime.h>
#include <cstdint>

// XLA CPU emits unfused mul/add (no fast-math, no contraction). hipcc defaults
// to -ffp-contract=fast -> must disable to mirror rounding exactly.
#pragma clang fp contract(off)

#define HH 50
#define SORB 64
#define NSAMP 4096
#define TOT (SORB * NSAMP)
#define RSLOTS 128
#define RSTRIDE 56   // floats per ring row: [0..49] h, [50] seq word
#define SPIN_FUEL (1 << 16)   // safety net: bounded spins (hang -> wrong answer)

typedef __attribute__((ext_vector_type(2))) float v2f;
typedef __attribute__((ext_vector_type(4))) float v4f;

// ---- XLA CPU EmitFastTanh (llvm_ir/math_ops.cc), with_fma = false ----
__device__ __forceinline__ float xla_tanh(float x) {
  const float kClamp = 7.90531110763549805f;
  float ax = fabsf(x);
  float xc = fminf(fmaxf(x, -kClamp), kClamp);
  float x2 = xc * xc;
  float p = -2.76076847742355e-16f;
  p = x2 * p + 2.00018790482477e-13f;
  p = x2 * p + -8.60467152213735e-11f;
  p = x2 * p + 5.12229709037114e-08f;
  p = x2 * p + 1.48572235717979e-05f;
  p = x2 * p + 6.37261928875436e-04f;
  p = x2 * p + 4.89352455891786e-03f;
  p = xc * p;
  float q = 1.19825839466702e-06f;
  q = x2 * q + 1.18534705686654e-04f;
  q = x2 * q + 2.26843463243900e-03f;
  q = x2 * q + 4.89352518554385e-03f;
  float r = p / q;
  return (ax < 0.0004f) ? x : r;
}

// XLA HLO kLogistic: 0.5 + 0.5 * tanh(0.5 * x)
__device__ __forceinline__ float xla_logistic(float x) {
  return 0.5f + 0.5f * xla_tanh(x * 0.5f);
}

// correctly-rounded f32 exp (matches glibc expf)
__device__ __forceinline__ float exp_cr(float x) {
  return (float)exp((double)x);
}

// ---- bit-exact Threefry-2x32 (20 rounds), as in jax/_src/prng.py ----
__device__ __forceinline__ void tf2x32(uint32_t k0, uint32_t k1,
                                       uint32_t c0, uint32_t c1,
                                       uint32_t& o0, uint32_t& o1) {
  uint32_t k2 = k0 ^ k1 ^ 0x1BD11BDAu;
  uint32_t x0 = c0 + k0, x1 = c1 + k1;
#define TF_R(d) { x0 += x1; x1 = (x1 << (d)) | (x1 >> (32 - (d))); x1 ^= x0; }
#define TF_GA TF_R(13) TF_R(15) TF_R(26) TF_R(6)
#define TF_GB TF_R(17) TF_R(29) TF_R(16) TF_R(24)
  TF_GA; x0 += k1; x1 += k2 + 1u;
  TF_GB; x0 += k2; x1 += k0 + 2u;
  TF_GA; x0 += k0; x1 += k1 + 3u;
  TF_GB; x0 += k1; x1 += k2 + 4u;
  TF_GA; x0 += k2; x1 += k0 + 5u;
#undef TF_GB
#undef TF_GA
#undef TF_R
  o0 = x0; o1 = x1;
}

// u_{i,j} = jax.random.uniform(fold_in(key(42), i), (4096,))[j]
__device__ __forceinline__ float u_for_cell(int cc) {
  int ii = cc >> 12;
  int jj = cc & (NSAMP - 1);
  uint32_t k0, k1;
  tf2x32(0u, 42u, 0u, (uint32_t)ii, k0, k1);   // fold_in: threefry(key, [0,i])
  uint32_t b0, b1;
  tf2x32(k0, k1, 0u, (uint32_t)jj, b0, b1);
  uint32_t bits = b0 ^ b1;                      // partitionable counter scheme
  return __uint_as_float((bits >> 9) | 0x3f800000u) - 1.0f;
}

// XLA RowMajorMatrixVectorProduct, vector width 8, no FMA — pairwise-vectorized.
// acc[l] <-> element 8ch+l; pairs: A0=[a0,a1] A1=[a2,a3] A2=[a4,a5] A3=[a6,a7].
// Tree ((a0+a4)+(a2+a6)) + ((a1+a5)+(a3+a7)) == (A0+A2)+(A1+A3) then .x+.y.
// Component-wise float2 mul/add is bit-identical to the proven scalar form.
__device__ __forceinline__ float dot_xla(const v2f* __restrict__ w,
                                         const v2f* __restrict__ h) {
  v2f A0 = w[0] * h[0];
  v2f A1 = w[1] * h[1];
  v2f A2 = w[2] * h[2];
  v2f A3 = w[3] * h[3];
#pragma unroll
  for (int ch = 1; ch < 6; ++ch) {
    A0 = A0 + w[4 * ch + 0] * h[4 * ch + 0];
    A1 = A1 + w[4 * ch + 1] * h[4 * ch + 1];
    A2 = A2 + w[4 * ch + 2] * h[4 * ch + 2];
    A3 = A3 + w[4 * ch + 3] * h[4 * ch + 3];
  }
  v2f S0 = A0 + A2;          // [s04, s15]
  v2f S1 = A1 + A3;          // [s26, s37]
  v2f T = S0 + S1;           // [t0, t1]
  float dot = T.x + T.y;
  dot = dot + w[24].x * h[24].x;   // scalar k-epilogue (k=48,49)
  dot = dot + w[24].y * h[24].y;
  return dot;
}

// Wave 0: the full 262144-cell sequential GRU chain. Lane t<50 owns W_hh rows
// {t, t+50, t+100} in VGPRs, so gh never leaves the consuming lane. h is
// broadcast through a 128-slot LDS ring; the h-write and a per-slot sequence
// word are issued in ONE ds_write_b32 (lane-dependent addr/data), so the
// in-order DS pipe makes seq-visible => h-visible for the sampler wave.
// Wave 1: fully asynchronous sampler (fc head + sqsoftmax + mask + threefry),
// 64 cells per batch, handshake via the seq words. One barrier at init only.
extern "C" __global__ void __launch_bounds__(128, 1)
ARSampler_59244778881183_kernel(const float* __restrict__ w_ih,
                                const float* __restrict__ w_hh,
                                const float* __restrict__ b_ih,
                                const float* __restrict__ b_hh,
                                const float* __restrict__ fc_w,
                                const float* __restrict__ fc_b,
                                int* __restrict__ out) {
  __shared__ __align__(16) float ring[RSLOTS][RSTRIDE];   // 28672 B
  __shared__ float sh_nu[NSAMP];                          // 16384 B
  __shared__ unsigned char sh_bits[2][NSAMP];             // 8192 B
  __shared__ unsigned int sh_done;

  const int t = threadIdx.x;
  const int lane = t & 63;

  // ---- LDS init by BOTH waves, then one barrier: kills the startup race on
  // stale cross-launch LDS (sh_done from a prior launch could let the chain
  // blow past backpressure and overwrite seq words -> mutual deadlock). ----
  if (t < 64) {
    for (int s = lane; s < RSLOTS; s += 64)
      ring[s][HH] = __uint_as_float(~0u);      // seq words: can't alias targets
    if (lane < HH) ring[RSLOTS - 1][lane] = 0.0f;  // h(-1) = 0
  } else {
    if (lane == 0) sh_done = 0u;
    for (int q = lane; q < NSAMP; q += 64) sh_nu[q] = 0.0f;
  }
  __syncthreads();

  if (t < 64) {
    // ================= chain wave =================
    const int tr = (lane < HH) ? lane : 0;   // clamped row id for idle lanes

    v2f wA[25], wB[25], wC[25];
#pragma unroll
    for (int k = 0; k < 25; ++k) {
      wA[k] = v2f{w_hh[tr * HH + 2 * k], w_hh[tr * HH + 2 * k + 1]};
      wB[k] = v2f{w_hh[(tr + 50) * HH + 2 * k], w_hh[(tr + 50) * HH + 2 * k + 1]};
      wC[k] = v2f{w_hh[(tr + 100) * HH + 2 * k], w_hh[(tr + 100) * HH + 2 * k + 1]};
    }
    const float bhr = b_hh[tr], bhz = b_hh[tr + 50], bhn = b_hh[tr + 100];
    const float xrb = b_ih[tr], xzb = b_ih[tr + 50], xnb = b_ih[tr + 100];
    const float xr0 = w_ih[tr * 2 + 0] + xrb;
    const float xr1 = w_ih[tr * 2 + 1] + xrb;
    const float xz0 = w_ih[(tr + 50) * 2 + 0] + xzb;
    const float xz1 = w_ih[(tr + 50) * 2 + 1] + xzb;
    const float xn0 = w_ih[(tr + 100) * 2 + 0] + xnb;
    const float xn1 = w_ih[(tr + 100) * 2 + 1] + xnb;
    float hold = 0.0f;

    volatile unsigned int* donep = &sh_done;

    for (int c = 0; c < TOT; ++c) {
      const int i = c >> 12;
      const int j = c & (NSAMP - 1);

      // backpressure vs sampler (ring + sh_bits reuse), once per 64 cells;
      // the sampler has large throughput headroom so this never truly spins.
      if ((c & 63) == 0 && c >= RSLOTS) {
        int fuel = SPIN_FUEL;
        while (*donep < (unsigned)(c - 64) && --fuel)
          __builtin_amdgcn_s_sleep(2);
        asm volatile("" ::: "memory");   // don't hoist sh_bits/ring reads above
      }

      // broadcast-read h from the slot written at the end of cell c-1
      const float* rp = ring[(c + RSLOTS - 1) & (RSLOTS - 1)];
      v2f hv[25];
#pragma unroll
      for (int m = 0; m < 13; ++m) {
        v4f f = *(const v4f*)(rp + 4 * m);
        hv[2 * m] = v2f{f.x, f.y};
        if (2 * m + 1 < 25) hv[2 * m + 1] = v2f{f.z, f.w};
      }

      // x-projection select (wave-uniform i; broadcast byte read of prev bit)
      float xr, xz, xn;
      if (i == 0) {
        xr = xrb; xz = xzb; xn = xnb;
      } else {
        unsigned b = sh_bits[(i - 1) & 1][j];
        xr = b ? xr1 : xr0;
        xz = b ? xz1 : xz0;
        xn = b ? xn1 : xn0;
      }

      // GEMV rows t, t+50, t+100 (all consumed locally, never leave the lane)
      const float ghr = dot_xla(wA, hv) + bhr;
      const float ghz = dot_xla(wB, hv) + bhz;
      const float ghn = dot_xla(wC, hv) + bhn;

      // GRU gates (exact op order of the proven R1 kernel)
      const float r = xla_logistic(xr + ghr);
      const float z = xla_logistic(xz + ghz);
      const float rhn = r * ghn;
      const float n = xla_tanh(xn + rhn);
      const float omz = 1.0f - z;
      const float hnew = omz * n + z * hold;
      hold = hnew;

      // combined write: lanes<50 write h, lanes>=50 write the seq word — one
      // ds_write_b32, so seq-visible implies h-visible (in-order DS pipe).
      const int wi = (lane < HH) ? lane : HH;
      const float wd = (lane < HH) ? hnew : __uint_as_float((unsigned)c);
      ring[c & (RSLOTS - 1)][wi] = wd;
    }
  } else {
    // ================= sampler wave (async, no barriers) =================
    float fw0[HH], fw1[HH];
#pragma unroll
    for (int k = 0; k < HH; ++k) {
      fw0[k] = fc_w[k];
      fw1[k] = fc_w[HH + k];
    }
    const float fb0 = fc_b[0], fb1 = fc_b[1];

    for (int B = 0; B < TOT; B += 64) {
      const int cc = B + lane;
      const int ii = B >> 12;                 // wave-uniform (4096 % 64 == 0)
      const int jj = cc & (NSAMP - 1);

      // wait until the chain published cell B+63 (seq values unique per cell;
      // post-barrier init means no stale value can alias a target)
      {
        const unsigned target = (unsigned)(B + 63);
        volatile unsigned int* sp =
            (volatile unsigned int*)&ring[(B + 63) & (RSLOTS - 1)][HH];
        int fuel = SPIN_FUEL;
        while (*sp != target && --fuel) __builtin_amdgcn_s_sleep(2);
        __builtin_amdgcn_s_sleep(1);   // cover sub-instruction LDS commit skew
        asm volatile("s_waitcnt lgkmcnt(0)" ::: "memory");
      }

      // read this lane's h vector (lane-distinct ring slots)
      const float* op = ring[cc & (RSLOTS - 1)];
      float o[52];
#pragma unroll
      for (int m = 0; m < 13; ++m) {
        v4f f = *(const v4f*)(op + 4 * m);
        o[4 * m + 0] = f.x; o[4 * m + 1] = f.y;
        o[4 * m + 2] = f.z; o[4 * m + 3] = f.w;
      }

      // logits (Eigen gebp: sequential-k FMA) + bias
      float l0 = 0.0f, l1 = 0.0f;
#pragma unroll
      for (int k = 0; k < HH; ++k) {
        l0 = fmaf(o[k], fw0[k], l0);
        l1 = fmaf(o[k], fw1[k], l1);
      }
      l0 = l0 + fb0;
      l1 = l1 + fb1;

      // sqrt(softmax)
      const float mx = fmaxf(l0, l1);
      const float e0 = exp_cr(l0 - mx);
      const float e1 = exp_cr(l1 - mx);
      const float se = e0 + e1;
      float o0 = sqrtf(e0 / se);
      float o1 = sqrtf(e1 / se);

      const float nuo = sh_nu[jj];
      if (ii >= SORB / 2) {
        const float fi = (float)ii;
        const float ndown = fi - nuo;
        const float ad = ((31.0f - ndown) >= 0.0f) ? 1.0f : 0.0f;
        const float au = ((31.0f - nuo) >= 0.0f) ? 1.0f : 0.0f;
        const float m0 = o0 * ad;
        const float m1 = o1 * au;
        float nr = sqrtf(m0 * m0 + m1 * m1);
        nr = fmaxf(nr, 1e-30f);
        o0 = m0 / nr;
        o1 = m1 / nr;
      }
      const float den = fmaxf(o0 + o1, 1e-30f);
      const float p0 = o0 / den;
      const float u = u_for_cell(cc);
      const int s = (u >= p0) ? 1 : 0;

      sh_nu[jj] = nuo + (float)s;
      sh_bits[ii & 1][jj] = (unsigned char)s;
      out[jj * SORB + ii] = s;   // samples.T

      // publish progress AFTER the bits/nu writes (in-order DS pipe; the asm
      // memory clobber keeps the compiler from sinking the stores past it)
      asm volatile("" ::: "memory");
      *(volatile unsigned int*)&sh_done = (unsigned)(B + 64);
    }
  }
}

extern "C" void kernel_launch(void* const* d_in, const int* in_sizes, int n_in,
                              void* d_out, int out_size, void* d_ws, size_t ws_size,
                              hipStream_t stream) {
  (void)in_sizes; (void)n_in; (void)out_size; (void)d_ws; (void)ws_size;
  const float* w_ih = (const float*)d_in[0];
  const float* w_hh = (const float*)d_in[1];
  const float* b_ih = (const float*)d_in[2];
  const float* b_hh = (const float*)d_in[3];
  const float* fc_w = (const float*)d_in[4];
  const float* fc_b = (const float*)d_in[5];
  hipLaunchKernelGGL(ARSampler_59244778881183_kernel, dim3(1), dim3(128), 0, stream,
                     w_ih, w_hh, b_ih, b_hh, fc_w, fc_b, (int*)d_out);
}